// Round 5
// baseline (443.197 us; speedup 1.0000x reference)
//
#include <hip/hip_runtime.h>

#define BDIM 2
#define SEQ  1568
#define DIM  768
#define NH   12
#define FR   8
#define NTOK 196
#define HD   64
#define MTOT (BDIM*SEQ)   // 3136 token rows
#define M2   (MTOT*FR)    // 25088 (t,f) rows for stage-2 GEMMs

typedef __attribute__((ext_vector_type(8))) short s16x8;   // 8 bf16 = 4 VGPRs
typedef __attribute__((ext_vector_type(4))) float f32x4;

static __device__ __forceinline__ float bf2f(ushort u) {
  return __uint_as_float(((unsigned)u) << 16);
}
static __device__ __forceinline__ ushort f2bf(float f) {
  unsigned u = __float_as_uint(f);
  unsigned r = (u + 0x7fffu + ((u >> 16) & 1u)) >> 16;
  return (ushort)r;
}
static __device__ __forceinline__ f32x4 mfma16(s16x8 a, s16x8 b, f32x4 c) {
  return __builtin_amdgcn_mfma_f32_16x16x32_bf16(a, b, c, 0, 0, 0);
}
// async global->LDS, 16B per lane; LDS dest = wave-uniform base + lane*16
static __device__ __forceinline__ void gload_lds16(const ushort* g, ushort* l) {
  __builtin_amdgcn_global_load_lds(
      (const __attribute__((address_space(1))) void*)g,
      (__attribute__((address_space(3))) void*)l, 16, 0, 0);
}

// ---------------------------------------------------------------------------
__global__ __launch_bounds__(256)
void cvt_bf16(const float* __restrict__ in, ushort* __restrict__ out, int n4) {
  int i = blockIdx.x*256 + threadIdx.x;
  if (i < n4) {
    float4 v = ((const float4*)in)[i];
    ushort4 o; o.x = f2bf(v.x); o.y = f2bf(v.y); o.z = f2bf(v.z); o.w = f2bf(v.w);
    ((ushort4*)out)[i] = o;
  }
}

// WT[N][K] = bf16(W[K][N]); 64x64 tiles. grid (N/64, K/64)
__global__ __launch_bounds__(256)
void cvt_wT(const float* __restrict__ W, ushort* __restrict__ WT, int N, int K) {
  __shared__ float T[64][65];
  const int tid = threadIdx.x;
  const int nx = blockIdx.x, ky = blockIdx.y;
  #pragma unroll
  for (int it = 0; it < 4; it++) {
    int idx = it*256 + tid;
    int r = idx >> 4, c4 = (idx & 15) << 2;
    float4 v = *(const float4*)&W[(size_t)(ky*64 + r)*N + nx*64 + c4];
    T[r][c4+0] = v.x; T[r][c4+1] = v.y; T[r][c4+2] = v.z; T[r][c4+3] = v.w;
  }
  __syncthreads();
  #pragma unroll
  for (int it = 0; it < 4; it++) {
    int idx = it*256 + tid;
    int n = idx >> 4, k4 = (idx & 15) << 2;
    ushort4 o;
    o.x = f2bf(T[k4+0][n]); o.y = f2bf(T[k4+1][n]);
    o.z = f2bf(T[k4+2][n]); o.w = f2bf(T[k4+3][n]);
    *(ushort4*)&WT[(size_t)(nx*64 + n)*K + ky*64 + k4] = o;
  }
}

// Vt[(b,f,h)][64][224] bf16, zero-padded n>=196. grid = 192
__global__ __launch_bounds__(256)
void vtrans(const ushort* __restrict__ kvbf, ushort* __restrict__ Vt) {
  __shared__ ushort Vl[NTOK][72];
  const int x = blockIdx.x;
  const int h = x % NH, f = (x / NH) % FR, b = x / (NH*FR);
  const int tid = threadIdx.x;
  for (int idx = tid; idx < NTOK*16; idx += 256) {
    int n = idx >> 4, c4 = (idx & 15) << 2;
    const ushort* p = kvbf + (size_t)(b*SEQ + f*NTOK + n)*(2*DIM) + DIM + h*HD + c4;
    *(ushort4*)&Vl[n][c4] = *(const ushort4*)p;
  }
  __syncthreads();
  ushort* vb = Vt + (size_t)x * (HD*224);
  for (int idx = tid; idx < 64*56; idx += 256) {
    int d = idx / 56, n4 = (idx % 56) << 2;
    ushort4 o;
    o.x = (n4+0 < NTOK) ? Vl[n4+0][d] : (ushort)0;
    o.y = (n4+1 < NTOK) ? Vl[n4+1][d] : (ushort)0;
    o.z = (n4+2 < NTOK) ? Vl[n4+2][d] : (ushort)0;
    o.w = (n4+3 < NTOK) ? Vl[n4+3][d] : (ushort)0;
    *(ushort4*)&vb[(size_t)d*224 + n4] = o;
  }
}

// ---------------------------------------------------------------------------
// bf16 MFMA GEMM, m97 structure: global_load_lds(16B) staging, [128][32] LDS,
// 2-barrier K-loop. Tile 128x128, BK=32, 256 threads, 2x2 waves x 4x4 frags.
// EPI: 0 = store C (OUT_BF16/BIAS/scale apply)
//      1 = logits: Lg[row*12 + head] = sum_col D[row][col]*q2[t][col] (per-head)
//      2 = zsum:   z[t][col] = sum_f D[(t,f)][col]*a2[t][h(col)][f]  (bf16)
// ---------------------------------------------------------------------------
template<int EPI, bool OUT_BF16, bool BIAS, bool DIAG>
__global__ __launch_bounds__(256)
void gemm_mfma(const ushort* __restrict__ A, const ushort* __restrict__ Bt,
               void* __restrict__ Cv, const float* __restrict__ bias,
               const float* __restrict__ q2g, const float* __restrict__ a2g,
               int M, int N, int K, float scale)
{
  __shared__ ushort As[128][32];
  __shared__ ushort Bs[128][32];
  extern __shared__ char dynlds[];     // EPI1: 8KB q2s; EPI2: 1KB a2s

  const int tid = threadIdx.x;
  const int bx = blockIdx.x, by = blockIdx.y;
  const int w = tid >> 6, lane = tid & 63;
  const int lq = lane & 15, quad = lane >> 4;
  const int wr = (w >> 1) * 64, wc = (w & 1) * 64;

  const int lrow = tid >> 2, lcol = (tid & 3) << 3;
  int ar0 = by*128 + lrow;       if (ar0 > M-1) ar0 = M-1;
  int ar1 = by*128 + 64 + lrow;  if (ar1 > M-1) ar1 = M-1;
  size_t aoff0, aoff1;
  if (DIAG) {
    int f0 = (ar0 % SEQ) / NTOK, f1 = (ar1 % SEQ) / NTOK;
    aoff0 = ((size_t)ar0*FR + f0)*DIM + lcol;
    aoff1 = ((size_t)ar1*FR + f1)*DIM + lcol;
  } else {
    aoff0 = (size_t)ar0*K + lcol;
    aoff1 = (size_t)ar1*K + lcol;
  }
  const size_t boff0 = (size_t)(bx*128 + lrow)*K + lcol;
  const size_t boff1 = (size_t)(bx*128 + 64 + lrow)*K + lcol;
  ushort* ldsA0 = &As[(w*16)][0];
  ushort* ldsA1 = &As[64 + w*16][0];
  ushort* ldsB0 = &Bs[(w*16)][0];
  ushort* ldsB1 = &Bs[64 + w*16][0];

  if (EPI == 1) {
    float* q2s = (float*)dynlds;                       // [16][128]
    int tt = tid >> 4, c0 = (tid & 15) << 3;
    const float* src = q2g + (size_t)(by*16 + tt)*DIM + bx*128 + c0;
    *(float4*)&q2s[tt*128 + c0]     = *(const float4*)src;
    *(float4*)&q2s[tt*128 + c0 + 4] = *(const float4*)(src + 4);
  }
  if (EPI == 2) {
    float* a2s = (float*)dynlds;                       // [16][16] = [t][h2*8+f]
    int tt = tid >> 4, idx = tid & 15;                 // idx = hh*8+f
    a2s[tt*16 + idx] =
        a2g[((size_t)(by*16 + tt)*NH + bx*2 + (idx >> 3))*FR + (idx & 7)];
  }

  f32x4 acc[4][4] = {};

  for (int k0 = 0; k0 < K; k0 += 32) {
    __syncthreads();
    gload_lds16(A  + aoff0 + k0, ldsA0);
    gload_lds16(A  + aoff1 + k0, ldsA1);
    gload_lds16(Bt + boff0 + k0, ldsB0);
    gload_lds16(Bt + boff1 + k0, ldsB1);
    __syncthreads();
    s16x8 af[4], bw[4];
    #pragma unroll
    for (int i = 0; i < 4; i++) af[i] = *(const s16x8*)&As[wr + i*16 + lq][quad*8];
    #pragma unroll
    for (int j = 0; j < 4; j++) bw[j] = *(const s16x8*)&Bs[wc + j*16 + lq][quad*8];
    #pragma unroll
    for (int i = 0; i < 4; i++)
      #pragma unroll
      for (int j = 0; j < 4; j++)
        acc[i][j] = mfma16(af[i], bw[j], acc[i][j]);
  }

  if (EPI == 0) {
    #pragma unroll
    for (int i = 0; i < 4; i++) {
      #pragma unroll
      for (int r = 0; r < 4; r++) {
        int row = by*128 + wr + i*16 + quad*4 + r;
        if (row < M) {
          #pragma unroll
          for (int j = 0; j < 4; j++) {
            int col = bx*128 + wc + j*16 + lq;
            float v = acc[i][j][r] * scale;
            if (BIAS) v += bias[col];
            if (OUT_BF16) ((ushort*)Cv)[(size_t)row*N + col] = f2bf(v);
            else          ((float*)Cv)[(size_t)row*N + col] = v;
          }
        }
      }
    }
  } else if (EPI == 1) {
    const float* q2s = (const float*)dynlds;
    float* Lg = (float*)Cv;
    const int head = bx*2 + (wc >> 6);
    #pragma unroll
    for (int i = 0; i < 4; i++) {
      #pragma unroll
      for (int r = 0; r < 4; r++) {
        int rl = wr + i*16 + quad*4 + r;
        int tt = rl >> 3;
        float p = 0.f;
        #pragma unroll
        for (int j = 0; j < 4; j++)
          p += acc[i][j][r] * q2s[tt*128 + wc + j*16 + lq];
        p += __shfl_xor(p, 1); p += __shfl_xor(p, 2);
        p += __shfl_xor(p, 4); p += __shfl_xor(p, 8);
        if (lq == 0)
          Lg[(size_t)(by*128 + rl)*NH + head] = p;
      }
    }
  } else {
    const float* a2s = (const float*)dynlds;
    ushort* zo = (ushort*)Cv;
    const int hh = wc >> 6;
    #pragma unroll
    for (int i = 0; i < 4; i++) {
      float zj[4] = {};
      #pragma unroll
      for (int r = 0; r < 4; r++) {
        int rl = wr + i*16 + quad*4 + r;
        int tt = rl >> 3, f = rl & 7;
        float a = a2s[tt*16 + hh*8 + f];
        #pragma unroll
        for (int j = 0; j < 4; j++) zj[j] += acc[i][j][r] * a;
      }
      #pragma unroll
      for (int j = 0; j < 4; j++) zj[j] += __shfl_xor(zj[j], 16);
      if ((quad & 1) == 0) {
        int tg = by*16 + ((wr + i*16 + quad*4) >> 3);
        #pragma unroll
        for (int j = 0; j < 4; j++) {
          int col = bx*128 + wc + j*16 + lq;
          zo[(size_t)tg*DIM + col] = f2bf(zj[j]);
        }
      }
    }
  }
}

// ---------------------------------------------------------------------------
// Stage 1 (MFMA, v2): one block = (64-query tile, b*h); f-loop INSIDE.
// Per frame: K_f cooperatively staged to LDS (shared by 4 waves), GEMM1 from
// LDS frags, softmax in regs, P -> per-wave LDS, GEMM2 w/ global Vt frags.
// Q-frags loaded once per block. LDS: Ks 29.3KB + P 29.0KB -> 2 blocks/CU.
// ---------------------------------------------------------------------------
__global__ __launch_bounds__(256)
void stage1_mfma(const ushort* __restrict__ qbf, const ushort* __restrict__ kvbf,
                 const ushort* __restrict__ Vt, ushort* __restrict__ x)
{
  __shared__ ushort Ks[208][72];    // stride 72: 4*lq%32 spread, optimal for b128
  __shared__ ushort P[4][16*232];   // per-wave; stride 232 likewise optimal

  const int qt = blockIdx.x;   // 0..24
  const int bh = blockIdx.y;   // 0..23
  const int b = bh / NH, h = bh % NH;
  const int tid = threadIdx.x;
  const int w = tid >> 6, lane = tid & 63;
  const int lq = lane & 15, quad = lane >> 4;

  // zero pad cols [208,224) of this wave's P rows (written once, never touched)
  {
    ushort4 zz; zz.x = 0; zz.y = 0; zz.z = 0; zz.w = 0;
    *(ushort4*)&P[w][lq*232 + 208 + quad*4] = zz;
  }

  // Q A-frags: loaded once, reused for all 8 frames
  int srow = qt*64 + w*16 + lq; if (srow > SEQ-1) srow = SEQ-1;
  const ushort* qp = qbf + ((size_t)b*SEQ + srow)*DIM + h*HD + quad*8;
  s16x8 aq0 = *(const s16x8*)(qp);
  s16x8 aq1 = *(const s16x8*)(qp + 32);

  // K staging map: chunk c = p*256+tid -> row c>>3, col (c&7)*8
  const int krow = tid >> 3, kcol = (tid & 7) << 3;

  for (int f = 0; f < FR; f++) {
    __syncthreads();   // all waves done reading Ks (prev frame's GEMM1)
    const ushort* kbase = kvbf + ((size_t)b*SEQ + f*NTOK)*(2*DIM) + h*HD + kcol;
    #pragma unroll
    for (int p = 0; p < 7; p++) {
      int row = krow + p*32;
      if (row < 208) {
        if (row < NTOK) {
          *(s16x8*)&Ks[row][kcol] = *(const s16x8*)(kbase + (size_t)row*(2*DIM));
        } else {
          ushort4 z4; z4.x = 0; z4.y = 0; z4.z = 0; z4.w = 0;
          *(ushort4*)&Ks[row][kcol]     = z4;
          *(ushort4*)&Ks[row][kcol + 4] = z4;
        }
      }
    }
    __syncthreads();

    // ---- GEMM1: S = Q K_f^T, B-frags from LDS ----
    f32x4 acc[13];
    #pragma unroll
    for (int nt = 0; nt < 13; nt++) {
      s16x8 bk0 = *(const s16x8*)&Ks[nt*16 + lq][quad*8];
      s16x8 bk1 = *(const s16x8*)&Ks[nt*16 + lq][32 + quad*8];
      f32x4 c = {};
      c = mfma16(aq0, bk0, c);
      c = mfma16(aq1, bk1, c);
      acc[nt] = c;
    }

    // ---- softmax (rows = quad*4+r, cols = lq across 13 frags) ----
    float mx[4], sm[4];
    #pragma unroll
    for (int r = 0; r < 4; r++) mx[r] = -1e30f;
    #pragma unroll
    for (int nt = 0; nt < 13; nt++) {
      bool valid = (nt < 12) || (lq < 4);
      #pragma unroll
      for (int r = 0; r < 4; r++) {
        float v = valid ? acc[nt][r] : -1e30f;
        acc[nt][r] = v;
        mx[r] = fmaxf(mx[r], v);
      }
    }
    #pragma unroll
    for (int r = 0; r < 4; r++) {
      float m = mx[r];
      m = fmaxf(m, __shfl_xor(m, 1)); m = fmaxf(m, __shfl_xor(m, 2));
      m = fmaxf(m, __shfl_xor(m, 4)); m = fmaxf(m, __shfl_xor(m, 8));
      mx[r] = m; sm[r] = 0.f;
    }
    #pragma unroll
    for (int nt = 0; nt < 13; nt++) {
      #pragma unroll
      for (int r = 0; r < 4; r++) {
        float v = acc[nt][r];
        float e = (v > -1e29f) ? __expf((v - mx[r]) * 0.125f) : 0.f;
        acc[nt][r] = e; sm[r] += e;
      }
    }
    #pragma unroll
    for (int r = 0; r < 4; r++) {
      float s = sm[r];
      s += __shfl_xor(s, 1); s += __shfl_xor(s, 2);
      s += __shfl_xor(s, 4); s += __shfl_xor(s, 8);
      sm[r] = 1.0f / s;
    }
    #pragma unroll
    for (int nt = 0; nt < 13; nt++)
      #pragma unroll
      for (int r = 0; r < 4; r++)
        P[w][(quad*4 + r)*232 + nt*16 + lq] = f2bf(acc[nt][r] * sm[r]);

    // ---- GEMM2: X = P V_f (per-wave P; Vt B-frags from global) ----
    const ushort* vb = Vt + ((size_t)((b*FR + f)*NH + h)) * (HD*224);
    f32x4 o[4] = {};
    #pragma unroll
    for (int ks = 0; ks < 7; ks++) {
      s16x8 ap = *(const s16x8*)&P[w][lq*232 + ks*32 + quad*8];
      #pragma unroll
      for (int dt = 0; dt < 4; dt++) {
        s16x8 bv = *(const s16x8*)(vb + (size_t)(dt*16 + lq)*224 + ks*32 + quad*8);
        o[dt] = mfma16(ap, bv, o[dt]);
      }
    }

    // ---- store x[b][s][f][h*64+d] bf16 ----
    int s0 = qt*64 + w*16 + quad*4;
    #pragma unroll
    for (int r = 0; r < 4; r++) {
      int s = s0 + r;
      if (s < SEQ) {
        size_t base = (((size_t)b*SEQ + s)*FR + f)*DIM + h*HD;
        #pragma unroll
        for (int dt = 0; dt < 4; dt++)
          x[base + dt*16 + lq] = f2bf(o[dt][r]);
      }
    }
  }
}

// ---------------------------------------------------------------------------
// Stage 2 softmax: Lg[(t*8+f)*12+h] -> attn2 (output) + a2buf[t][h][f]
// ---------------------------------------------------------------------------
__global__ __launch_bounds__(256)
void stage2_softmax(const float* __restrict__ Lg, float* __restrict__ attn2,
                    float* __restrict__ a2buf)
{
  int gid = blockIdx.x*256 + threadIdx.x;
  if (gid >= MTOT*NH) return;
  int t = gid / NH, h = gid % NH;
  int b = t / SEQ, s = t % SEQ;
  float v[8], m = -1e30f;
  #pragma unroll
  for (int f = 0; f < 8; f++) {
    v[f] = Lg[(size_t)(t*FR + f)*NH + h];
    m = fmaxf(m, v[f]);
  }
  float sum = 0.f;
  #pragma unroll
  for (int f = 0; f < 8; f++) { v[f] = __expf(v[f] - m); sum += v[f]; }
  float inv = 1.0f / sum;
  float* ao = attn2 + ((size_t)(b*NH + h)*SEQ + s)*FR;
  float* ab = a2buf + (size_t)gid*FR;
  #pragma unroll
  for (int f = 0; f < 8; f++) {
    float a = v[f] * inv;
    ao[f] = a; ab[f] = a;
  }
}

// ---------------------------------------------------------------------------
// Workspace (ushort units; 68.5 MB total, same known-good map):
//  xbf @0 | kvbf/q2 | qbf/zbf | xqbf (Vt / Lg+a2buf alias) | xkbf
//  WqT | WkvT (WpkvT alias) | WpqT | WprT
// ---------------------------------------------------------------------------
extern "C" void kernel_launch(void* const* d_in, const int* in_sizes, int n_in,
                              void* d_out, int out_size, void* d_ws, size_t ws_size,
                              hipStream_t stream) {
  const float* xq    = (const float*)d_in[0];
  const float* xk    = (const float*)d_in[1];
  const float* Wq    = (const float*)d_in[2];
  const float* Wkv   = (const float*)d_in[3];
  const float* Wpq   = (const float*)d_in[4];
  const float* Wpkv  = (const float*)d_in[5];
  const float* Wproj = (const float*)d_in[6];
  const float* bproj = (const float*)d_in[7];

  float* out   = (float*)d_out;
  float* attn2 = out + (size_t)MTOT*DIM;

  ushort* ws    = (ushort*)d_ws;
  ushort* xbf   = ws;
  ushort* kvbf  = xbf + (size_t)MTOT*FR*DIM;
  float*  q2    = (float*)kvbf;                 // alias, post-stage1
  ushort* qbf   = kvbf + (size_t)MTOT*2*DIM;
  ushort* zbf   = qbf;                          // alias, post-stage1
  ushort* xqbf  = qbf + (size_t)MTOT*DIM;
  ushort* xkbf  = xqbf + (size_t)MTOT*DIM;
  ushort* Vt    = xqbf;                         // alias (fits)
  float*  Lg    = (float*)xqbf;                 // alias, post-stage1
  float*  a2buf = Lg + (size_t)M2*NH;
  ushort* WqT   = xkbf + (size_t)MTOT*DIM;
  ushort* WkvT  = WqT  + (size_t)DIM*DIM;
  ushort* WpkvT = WkvT;                         // alias, post-kv-GEMM
  ushort* WpqT  = WkvT + (size_t)2*DIM*DIM;
  ushort* WprT  = WpqT + (size_t)DIM*DIM;

  dim3 blk(256);
  const int n4 = MTOT*DIM/4;

  cvt_bf16<<<dim3((n4+255)/256), blk, 0, stream>>>(xq, xqbf, n4);
  cvt_bf16<<<dim3((n4+255)/256), blk, 0, stream>>>(xk, xkbf, n4);
  cvt_wT<<<dim3(DIM/64, DIM/64), blk, 0, stream>>>(Wq,    WqT,  DIM,   DIM);
  cvt_wT<<<dim3(2*DIM/64, DIM/64), blk, 0, stream>>>(Wkv, WkvT, 2*DIM, DIM);
  cvt_wT<<<dim3(DIM/64, DIM/64), blk, 0, stream>>>(Wpq,   WpqT, DIM,   DIM);
  cvt_wT<<<dim3(DIM/64, DIM/64), blk, 0, stream>>>(Wproj, WprT, DIM,   DIM);

  gemm_mfma<0,true,false,false><<<dim3(DIM/128, (MTOT+127)/128), blk, 0, stream>>>(
      xqbf, WqT, qbf, nullptr, nullptr, nullptr, MTOT, DIM, DIM, 1.0f);
  gemm_mfma<0,true,false,false><<<dim3(2*DIM/128, (MTOT+127)/128), blk, 0, stream>>>(
      xkbf, WkvT, kvbf, nullptr, nullptr, nullptr, MTOT, 2*DIM, DIM, 1.0f);
  cvt_wT<<<dim3(2*DIM/64, DIM/64), blk, 0, stream>>>(Wpkv, WpkvT, 2*DIM, DIM);
  vtrans<<<dim3(BDIM*FR*NH), blk, 0, stream>>>(kvbf, Vt);
  // stage 1 (new grid: qtile x bh; f-loop inside)
  stage1_mfma<<<dim3((SEQ+63)/64, BDIM*NH), blk, 0, stream>>>(qbf, kvbf, Vt, xbf);
  gemm_mfma<0,false,false,true><<<dim3(DIM/128, (MTOT+127)/128), blk, 0, stream>>>(
      xbf, WpqT, q2, nullptr, nullptr, nullptr, MTOT, DIM, DIM, 0.125f);
  gemm_mfma<1,false,false,false><<<dim3(DIM/128, M2/128), blk, 8192, stream>>>(
      xbf, WpkvT, Lg, nullptr, q2, nullptr, M2, DIM, DIM, 1.0f);
  stage2_softmax<<<dim3((MTOT*NH+255)/256), blk, 0, stream>>>(Lg, attn2, a2buf);
  gemm_mfma<2,false,false,false><<<dim3(DIM/128, M2/128), blk, 1024, stream>>>(
      xbf, WpkvT + (size_t)DIM*DIM, zbf, nullptr, nullptr, a2buf, M2, DIM, DIM, 1.0f);
  gemm_mfma<0,false,true,false><<<dim3(DIM/128, (MTOT+127)/128), blk, 0, stream>>>(
      zbf, WprT, out, bproj, nullptr, nullptr, MTOT, DIM, DIM, 1.0f);
}

// Round 6
// 373.003 us; speedup vs baseline: 1.1882x; 1.1882x over previous
//
#include <hip/hip_runtime.h>

#define BDIM 2
#define SEQ  1568
#define DIM  768
#define NH   12
#define FR   8
#define NTOK 196
#define HD   64
#define MTOT (BDIM*SEQ)   // 3136 token rows
#define M2   (MTOT*FR)    // 25088 (t,f) rows for stage-2 GEMMs

typedef __attribute__((ext_vector_type(8))) short s16x8;   // 8 bf16 = 4 VGPRs
typedef __attribute__((ext_vector_type(4))) float f32x4;

static __device__ __forceinline__ float bf2f(ushort u) {
  return __uint_as_float(((unsigned)u) << 16);
}
static __device__ __forceinline__ ushort f2bf(float f) {
  unsigned u = __float_as_uint(f);
  unsigned r = (u + 0x7fffu + ((u >> 16) & 1u)) >> 16;
  return (ushort)r;
}
static __device__ __forceinline__ f32x4 mfma16(s16x8 a, s16x8 b, f32x4 c) {
  return __builtin_amdgcn_mfma_f32_16x16x32_bf16(a, b, c, 0, 0, 0);
}
// async global->LDS, 16B per lane; LDS dest = wave-uniform base + lane*16
static __device__ __forceinline__ void gload_lds16(const ushort* g, ushort* l) {
  __builtin_amdgcn_global_load_lds(
      (const __attribute__((address_space(1))) void*)g,
      (__attribute__((address_space(3))) void*)l, 16, 0, 0);
}

// ---------------------------------------------------------------------------
__global__ __launch_bounds__(256)
void cvt_bf16(const float* __restrict__ in, ushort* __restrict__ out, int n4) {
  int i = blockIdx.x*256 + threadIdx.x;
  if (i < n4) {
    float4 v = ((const float4*)in)[i];
    ushort4 o; o.x = f2bf(v.x); o.y = f2bf(v.y); o.z = f2bf(v.z); o.w = f2bf(v.w);
    ((ushort4*)out)[i] = o;
  }
}

// WT[N][K] = bf16(W[K][N]); 64x64 tiles. grid (N/64, K/64)
__global__ __launch_bounds__(256)
void cvt_wT(const float* __restrict__ W, ushort* __restrict__ WT, int N, int K) {
  __shared__ float T[64][65];
  const int tid = threadIdx.x;
  const int nx = blockIdx.x, ky = blockIdx.y;
  #pragma unroll
  for (int it = 0; it < 4; it++) {
    int idx = it*256 + tid;
    int r = idx >> 4, c4 = (idx & 15) << 2;
    float4 v = *(const float4*)&W[(size_t)(ky*64 + r)*N + nx*64 + c4];
    T[r][c4+0] = v.x; T[r][c4+1] = v.y; T[r][c4+2] = v.z; T[r][c4+3] = v.w;
  }
  __syncthreads();
  #pragma unroll
  for (int it = 0; it < 4; it++) {
    int idx = it*256 + tid;
    int n = idx >> 4, k4 = (idx & 15) << 2;
    ushort4 o;
    o.x = f2bf(T[k4+0][n]); o.y = f2bf(T[k4+1][n]);
    o.z = f2bf(T[k4+2][n]); o.w = f2bf(T[k4+3][n]);
    *(ushort4*)&WT[(size_t)(nx*64 + n)*K + ky*64 + k4] = o;
  }
}

// Vt[(b,f,h)][64][224] bf16, zero-padded n>=196. grid = 192
__global__ __launch_bounds__(256)
void vtrans(const ushort* __restrict__ kvbf, ushort* __restrict__ Vt) {
  __shared__ ushort Vl[NTOK][72];
  const int x = blockIdx.x;
  const int h = x % NH, f = (x / NH) % FR, b = x / (NH*FR);
  const int tid = threadIdx.x;
  for (int idx = tid; idx < NTOK*16; idx += 256) {
    int n = idx >> 4, c4 = (idx & 15) << 2;
    const ushort* p = kvbf + (size_t)(b*SEQ + f*NTOK + n)*(2*DIM) + DIM + h*HD + c4;
    *(ushort4*)&Vl[n][c4] = *(const ushort4*)p;
  }
  __syncthreads();
  ushort* vb = Vt + (size_t)x * (HD*224);
  for (int idx = tid; idx < 64*56; idx += 256) {
    int d = idx / 56, n4 = (idx % 56) << 2;
    ushort4 o;
    o.x = (n4+0 < NTOK) ? Vl[n4+0][d] : (ushort)0;
    o.y = (n4+1 < NTOK) ? Vl[n4+1][d] : (ushort)0;
    o.z = (n4+2 < NTOK) ? Vl[n4+2][d] : (ushort)0;
    o.w = (n4+3 < NTOK) ? Vl[n4+3][d] : (ushort)0;
    *(ushort4*)&vb[(size_t)d*224 + n4] = o;
  }
}

// ---------------------------------------------------------------------------
// bf16 MFMA GEMM, m97 structure. Tile 128x128, BK=32, 256 threads.
// EPI: 0 = store C; 1 = logits epilogue; 2 = zsum epilogue.
// ---------------------------------------------------------------------------
template<int EPI, bool OUT_BF16, bool BIAS, bool DIAG>
__global__ __launch_bounds__(256)
void gemm_mfma(const ushort* __restrict__ A, const ushort* __restrict__ Bt,
               void* __restrict__ Cv, const float* __restrict__ bias,
               const float* __restrict__ q2g, const float* __restrict__ a2g,
               int M, int N, int K, float scale)
{
  __shared__ ushort As[128][32];
  __shared__ ushort Bs[128][32];
  extern __shared__ char dynlds[];     // EPI1: 8KB q2s; EPI2: 1KB a2s

  const int tid = threadIdx.x;
  const int bx = blockIdx.x, by = blockIdx.y;
  const int w = tid >> 6, lane = tid & 63;
  const int lq = lane & 15, quad = lane >> 4;
  const int wr = (w >> 1) * 64, wc = (w & 1) * 64;

  const int lrow = tid >> 2, lcol = (tid & 3) << 3;
  int ar0 = by*128 + lrow;       if (ar0 > M-1) ar0 = M-1;
  int ar1 = by*128 + 64 + lrow;  if (ar1 > M-1) ar1 = M-1;
  size_t aoff0, aoff1;
  if (DIAG) {
    int f0 = (ar0 % SEQ) / NTOK, f1 = (ar1 % SEQ) / NTOK;
    aoff0 = ((size_t)ar0*FR + f0)*DIM + lcol;
    aoff1 = ((size_t)ar1*FR + f1)*DIM + lcol;
  } else {
    aoff0 = (size_t)ar0*K + lcol;
    aoff1 = (size_t)ar1*K + lcol;
  }
  const size_t boff0 = (size_t)(bx*128 + lrow)*K + lcol;
  const size_t boff1 = (size_t)(bx*128 + 64 + lrow)*K + lcol;
  ushort* ldsA0 = &As[(w*16)][0];
  ushort* ldsA1 = &As[64 + w*16][0];
  ushort* ldsB0 = &Bs[(w*16)][0];
  ushort* ldsB1 = &Bs[64 + w*16][0];

  if (EPI == 1) {
    float* q2s = (float*)dynlds;                       // [16][128]
    int tt = tid >> 4, c0 = (tid & 15) << 3;
    const float* src = q2g + (size_t)(by*16 + tt)*DIM + bx*128 + c0;
    *(float4*)&q2s[tt*128 + c0]     = *(const float4*)src;
    *(float4*)&q2s[tt*128 + c0 + 4] = *(const float4*)(src + 4);
  }
  if (EPI == 2) {
    float* a2s = (float*)dynlds;                       // [16][16] = [t][h2*8+f]
    int tt = tid >> 4, idx = tid & 15;                 // idx = hh*8+f
    a2s[tt*16 + idx] =
        a2g[((size_t)(by*16 + tt)*NH + bx*2 + (idx >> 3))*FR + (idx & 7)];
  }

  f32x4 acc[4][4] = {};

  for (int k0 = 0; k0 < K; k0 += 32) {
    __syncthreads();
    gload_lds16(A  + aoff0 + k0, ldsA0);
    gload_lds16(A  + aoff1 + k0, ldsA1);
    gload_lds16(Bt + boff0 + k0, ldsB0);
    gload_lds16(Bt + boff1 + k0, ldsB1);
    __syncthreads();
    s16x8 af[4], bw[4];
    #pragma unroll
    for (int i = 0; i < 4; i++) af[i] = *(const s16x8*)&As[wr + i*16 + lq][quad*8];
    #pragma unroll
    for (int j = 0; j < 4; j++) bw[j] = *(const s16x8*)&Bs[wc + j*16 + lq][quad*8];
    #pragma unroll
    for (int i = 0; i < 4; i++)
      #pragma unroll
      for (int j = 0; j < 4; j++)
        acc[i][j] = mfma16(af[i], bw[j], acc[i][j]);
  }

  if (EPI == 0) {
    #pragma unroll
    for (int i = 0; i < 4; i++) {
      #pragma unroll
      for (int r = 0; r < 4; r++) {
        int row = by*128 + wr + i*16 + quad*4 + r;
        if (row < M) {
          #pragma unroll
          for (int j = 0; j < 4; j++) {
            int col = bx*128 + wc + j*16 + lq;
            float v = acc[i][j][r] * scale;
            if (BIAS) v += bias[col];
            if (OUT_BF16) ((ushort*)Cv)[(size_t)row*N + col] = f2bf(v);
            else          ((float*)Cv)[(size_t)row*N + col] = v;
          }
        }
      }
    }
  } else if (EPI == 1) {
    const float* q2s = (const float*)dynlds;
    float* Lg = (float*)Cv;
    const int head = bx*2 + (wc >> 6);
    #pragma unroll
    for (int i = 0; i < 4; i++) {
      #pragma unroll
      for (int r = 0; r < 4; r++) {
        int rl = wr + i*16 + quad*4 + r;
        int tt = rl >> 3;
        float p = 0.f;
        #pragma unroll
        for (int j = 0; j < 4; j++)
          p += acc[i][j][r] * q2s[tt*128 + wc + j*16 + lq];
        p += __shfl_xor(p, 1); p += __shfl_xor(p, 2);
        p += __shfl_xor(p, 4); p += __shfl_xor(p, 8);
        if (lq == 0)
          Lg[(size_t)(by*128 + rl)*NH + head] = p;
      }
    }
  } else {
    const float* a2s = (const float*)dynlds;
    ushort* zo = (ushort*)Cv;
    const int hh = wc >> 6;
    #pragma unroll
    for (int i = 0; i < 4; i++) {
      float zj[4] = {};
      #pragma unroll
      for (int r = 0; r < 4; r++) {
        int rl = wr + i*16 + quad*4 + r;
        int tt = rl >> 3, f = rl & 7;
        float a = a2s[tt*16 + hh*8 + f];
        #pragma unroll
        for (int j = 0; j < 4; j++) zj[j] += acc[i][j][r] * a;
      }
      #pragma unroll
      for (int j = 0; j < 4; j++) zj[j] += __shfl_xor(zj[j], 16);
      if ((quad & 1) == 0) {
        int tg = by*16 + ((wr + i*16 + quad*4) >> 3);
        #pragma unroll
        for (int j = 0; j < 4; j++) {
          int col = bx*128 + wc + j*16 + lq;
          zo[(size_t)tg*DIM + col] = f2bf(zj[j]);
        }
      }
    }
  }
}

// ---------------------------------------------------------------------------
// Stage 1 (MFMA, v3): grid (25 qtiles, 8 frames, 24 bh) — f back in grid for
// load balance. K_f staged once per block into LDS (shared by 4 waves); after
// GEMM1 + a barrier, the P buffer ALIASES the dead Ks region, so LDS stays at
// 29.9 KB (~5 blocks/CU) instead of round-5's 59.9 KB (1-2 blocks/CU).
// ---------------------------------------------------------------------------
__global__ __launch_bounds__(256)
void stage1_mfma(const ushort* __restrict__ qbf, const ushort* __restrict__ kvbf,
                 const ushort* __restrict__ Vt, ushort* __restrict__ x)
{
  __shared__ ushort sh[208*72];     // Ks[208][72] (29952B); P[4][16*232] aliases

  const int qt = blockIdx.x;   // 0..24
  const int f  = blockIdx.y;   // 0..7
  const int bh = blockIdx.z;   // 0..23
  const int b = bh / NH, h = bh % NH;
  const int tid = threadIdx.x;
  const int w = tid >> 6, lane = tid & 63;
  const int lq = lane & 15, quad = lane >> 4;

  // Q A-frags (issue early; reused for the whole block)
  int srow = qt*64 + w*16 + lq; if (srow > SEQ-1) srow = SEQ-1;
  const ushort* qp = qbf + ((size_t)b*SEQ + srow)*DIM + h*HD + quad*8;
  s16x8 aq0 = *(const s16x8*)(qp);
  s16x8 aq1 = *(const s16x8*)(qp + 32);

  // ---- stage K_f into LDS: row = tid>>3 (+32/iter), col = (tid&7)*8 ----
  const int krow = tid >> 3, kcol = (tid & 7) << 3;
  const ushort* kbase = kvbf + ((size_t)b*SEQ + f*NTOK)*(2*DIM) + h*HD + kcol;
  #pragma unroll
  for (int p = 0; p < 7; p++) {
    int row = krow + p*32;
    if (row < 208) {
      if (row < NTOK) {
        *(s16x8*)&sh[row*72 + kcol] = *(const s16x8*)(kbase + (size_t)row*(2*DIM));
      } else {
        ushort4 z4; z4.x = 0; z4.y = 0; z4.z = 0; z4.w = 0;
        *(ushort4*)&sh[row*72 + kcol]     = z4;
        *(ushort4*)&sh[row*72 + kcol + 4] = z4;
      }
    }
  }
  __syncthreads();

  // ---- GEMM1: S = Q K_f^T, B-frags from LDS ----
  f32x4 acc[13];
  #pragma unroll
  for (int nt = 0; nt < 13; nt++) {
    s16x8 bk0 = *(const s16x8*)&sh[(nt*16 + lq)*72 + quad*8];
    s16x8 bk1 = *(const s16x8*)&sh[(nt*16 + lq)*72 + 32 + quad*8];
    f32x4 c = {};
    c = mfma16(aq0, bk0, c);
    c = mfma16(aq1, bk1, c);
    acc[nt] = c;
  }

  // ---- softmax (rows = quad*4+r, cols = lq across 13 frags) ----
  float mx[4], sm[4];
  #pragma unroll
  for (int r = 0; r < 4; r++) mx[r] = -1e30f;
  #pragma unroll
  for (int nt = 0; nt < 13; nt++) {
    bool valid = (nt < 12) || (lq < 4);
    #pragma unroll
    for (int r = 0; r < 4; r++) {
      float v = valid ? acc[nt][r] : -1e30f;
      acc[nt][r] = v;
      mx[r] = fmaxf(mx[r], v);
    }
  }
  #pragma unroll
  for (int r = 0; r < 4; r++) {
    float m = mx[r];
    m = fmaxf(m, __shfl_xor(m, 1)); m = fmaxf(m, __shfl_xor(m, 2));
    m = fmaxf(m, __shfl_xor(m, 4)); m = fmaxf(m, __shfl_xor(m, 8));
    mx[r] = m; sm[r] = 0.f;
  }
  #pragma unroll
  for (int nt = 0; nt < 13; nt++) {
    #pragma unroll
    for (int r = 0; r < 4; r++) {
      float v = acc[nt][r];
      float e = (v > -1e29f) ? __expf((v - mx[r]) * 0.125f) : 0.f;
      acc[nt][r] = e; sm[r] += e;
    }
  }
  #pragma unroll
  for (int r = 0; r < 4; r++) {
    float s = sm[r];
    s += __shfl_xor(s, 1); s += __shfl_xor(s, 2);
    s += __shfl_xor(s, 4); s += __shfl_xor(s, 8);
    sm[r] = 1.0f / s;
  }

  __syncthreads();   // all waves done reading Ks -> safe to overwrite with P

  // ---- P into LDS (aliases Ks region); per-wave segment ----
  ushort* Pw = sh + w*(16*232);
  {
    ushort4 zz; zz.x = 0; zz.y = 0; zz.z = 0; zz.w = 0;
    *(ushort4*)&Pw[lq*232 + 208 + quad*4] = zz;   // zero pad cols [208,224)
  }
  #pragma unroll
  for (int nt = 0; nt < 13; nt++)
    #pragma unroll
    for (int r = 0; r < 4; r++)
      Pw[(quad*4 + r)*232 + nt*16 + lq] = f2bf(acc[nt][r] * sm[r]);

  // ---- GEMM2: X = P V_f (per-wave P; Vt B-frags from global) ----
  const ushort* vb = Vt + ((size_t)((b*FR + f)*NH + h)) * (HD*224);
  f32x4 o[4] = {};
  #pragma unroll
  for (int ks = 0; ks < 7; ks++) {
    s16x8 ap = *(const s16x8*)&Pw[lq*232 + ks*32 + quad*8];
    #pragma unroll
    for (int dt = 0; dt < 4; dt++) {
      s16x8 bv = *(const s16x8*)(vb + (size_t)(dt*16 + lq)*224 + ks*32 + quad*8);
      o[dt] = mfma16(ap, bv, o[dt]);
    }
  }

  // ---- store x[b][s][f][h*64+d] bf16 ----
  int s0 = qt*64 + w*16 + quad*4;
  #pragma unroll
  for (int r = 0; r < 4; r++) {
    int s = s0 + r;
    if (s < SEQ) {
      size_t base = (((size_t)b*SEQ + s)*FR + f)*DIM + h*HD;
      #pragma unroll
      for (int dt = 0; dt < 4; dt++)
        x[base + dt*16 + lq] = f2bf(o[dt][r]);
    }
  }
}

// ---------------------------------------------------------------------------
// Stage 2 softmax: Lg[(t*8+f)*12+h] -> attn2 (output) + a2buf[t][h][f]
// ---------------------------------------------------------------------------
__global__ __launch_bounds__(256)
void stage2_softmax(const float* __restrict__ Lg, float* __restrict__ attn2,
                    float* __restrict__ a2buf)
{
  int gid = blockIdx.x*256 + threadIdx.x;
  if (gid >= MTOT*NH) return;
  int t = gid / NH, h = gid % NH;
  int b = t / SEQ, s = t % SEQ;
  float v[8], m = -1e30f;
  #pragma unroll
  for (int f = 0; f < 8; f++) {
    v[f] = Lg[(size_t)(t*FR + f)*NH + h];
    m = fmaxf(m, v[f]);
  }
  float sum = 0.f;
  #pragma unroll
  for (int f = 0; f < 8; f++) { v[f] = __expf(v[f] - m); sum += v[f]; }
  float inv = 1.0f / sum;
  float* ao = attn2 + ((size_t)(b*NH + h)*SEQ + s)*FR;
  float* ab = a2buf + (size_t)gid*FR;
  #pragma unroll
  for (int f = 0; f < 8; f++) {
    float a = v[f] * inv;
    ao[f] = a; ab[f] = a;
  }
}

// ---------------------------------------------------------------------------
// Workspace (ushort units; 68.5 MB total, same known-good map):
//  xbf @0 | kvbf/q2 | qbf/zbf | xqbf (Vt / Lg+a2buf alias) | xkbf
//  WqT | WkvT (WpkvT alias) | WpqT | WprT
// ---------------------------------------------------------------------------
extern "C" void kernel_launch(void* const* d_in, const int* in_sizes, int n_in,
                              void* d_out, int out_size, void* d_ws, size_t ws_size,
                              hipStream_t stream) {
  const float* xq    = (const float*)d_in[0];
  const float* xk    = (const float*)d_in[1];
  const float* Wq    = (const float*)d_in[2];
  const float* Wkv   = (const float*)d_in[3];
  const float* Wpq   = (const float*)d_in[4];
  const float* Wpkv  = (const float*)d_in[5];
  const float* Wproj = (const float*)d_in[6];
  const float* bproj = (const float*)d_in[7];

  float* out   = (float*)d_out;
  float* attn2 = out + (size_t)MTOT*DIM;

  ushort* ws    = (ushort*)d_ws;
  ushort* xbf   = ws;
  ushort* kvbf  = xbf + (size_t)MTOT*FR*DIM;
  float*  q2    = (float*)kvbf;                 // alias, post-stage1
  ushort* qbf   = kvbf + (size_t)MTOT*2*DIM;
  ushort* zbf   = qbf;                          // alias, post-stage1
  ushort* xqbf  = qbf + (size_t)MTOT*DIM;
  ushort* xkbf  = xqbf + (size_t)MTOT*DIM;
  ushort* Vt    = xqbf;                         // alias (fits)
  float*  Lg    = (float*)xqbf;                 // alias, post-stage1
  float*  a2buf = Lg + (size_t)M2*NH;
  ushort* WqT   = xkbf + (size_t)MTOT*DIM;
  ushort* WkvT  = WqT  + (size_t)DIM*DIM;
  ushort* WpkvT = WkvT;                         // alias, post-kv-GEMM
  ushort* WpqT  = WkvT + (size_t)2*DIM*DIM;
  ushort* WprT  = WpqT + (size_t)DIM*DIM;

  dim3 blk(256);
  const int n4 = MTOT*DIM/4;

  cvt_bf16<<<dim3((n4+255)/256), blk, 0, stream>>>(xq, xqbf, n4);
  cvt_bf16<<<dim3((n4+255)/256), blk, 0, stream>>>(xk, xkbf, n4);
  cvt_wT<<<dim3(DIM/64, DIM/64), blk, 0, stream>>>(Wq,    WqT,  DIM,   DIM);
  cvt_wT<<<dim3(2*DIM/64, DIM/64), blk, 0, stream>>>(Wkv, WkvT, 2*DIM, DIM);
  cvt_wT<<<dim3(DIM/64, DIM/64), blk, 0, stream>>>(Wpq,   WpqT, DIM,   DIM);
  cvt_wT<<<dim3(DIM/64, DIM/64), blk, 0, stream>>>(Wproj, WprT, DIM,   DIM);

  gemm_mfma<0,true,false,false><<<dim3(DIM/128, (MTOT+127)/128), blk, 0, stream>>>(
      xqbf, WqT, qbf, nullptr, nullptr, nullptr, MTOT, DIM, DIM, 1.0f);
  gemm_mfma<0,true,false,false><<<dim3(2*DIM/128, (MTOT+127)/128), blk, 0, stream>>>(
      xkbf, WkvT, kvbf, nullptr, nullptr, nullptr, MTOT, 2*DIM, DIM, 1.0f);
  cvt_wT<<<dim3(2*DIM/64, DIM/64), blk, 0, stream>>>(Wpkv, WpkvT, 2*DIM, DIM);
  vtrans<<<dim3(BDIM*FR*NH), blk, 0, stream>>>(kvbf, Vt);
  // stage 1 (f in grid; LDS-shared K with P aliasing)
  stage1_mfma<<<dim3((SEQ+63)/64, FR, BDIM*NH), blk, 0, stream>>>(qbf, kvbf, Vt, xbf);
  gemm_mfma<0,false,false,true><<<dim3(DIM/128, (MTOT+127)/128), blk, 0, stream>>>(
      xbf, WpqT, q2, nullptr, nullptr, nullptr, MTOT, DIM, DIM, 0.125f);
  gemm_mfma<1,false,false,false><<<dim3(DIM/128, M2/128), blk, 8192, stream>>>(
      xbf, WpkvT, Lg, nullptr, q2, nullptr, M2, DIM, DIM, 1.0f);
  stage2_softmax<<<dim3((MTOT*NH+255)/256), blk, 0, stream>>>(Lg, attn2, a2buf);
  gemm_mfma<2,false,false,false><<<dim3(DIM/128, M2/128), blk, 1024, stream>>>(
      xbf, WpkvT + (size_t)DIM*DIM, zbf, nullptr, nullptr, a2buf, M2, DIM, DIM, 1.0f);
  gemm_mfma<0,false,true,false><<<dim3(DIM/128, (MTOT+127)/128), blk, 0, stream>>>(
      zbf, WprT, out, bproj, nullptr, nullptr, MTOT, DIM, DIM, 1.0f);
}